// Round 1
// 77.024 us; speedup vs baseline: 1.1107x; 1.1107x over previous
//
#include <hip/hip_runtime.h>
#include <math.h>

#define Bsz 2048
#define Ddim 32
#define Nsz 8192
#define Kk 30
#define TPB 256
#define ROWS 4                  // rows (i) per block, in registers
#define JCH (Bsz / TPB)         // 8 chunks of 256 j's: each block sees ALL j
#define NBLK (Bsz / ROWS)       // 512 blocks = 2/CU, single fully-resident round
#define NW (Nsz / 32)           // 256 bitset words per row

// JSL=1 restructure: each block owns rows i0..i0+3 against the FULL j range,
// so den/num are complete in-block and the per-row loss (-log(num/den+eps))
// is computed here. Workspace shrinks to 512 (loss, count) pairs, pure
// overwrite (no zero-init). samp[j] is read directly from global (coalesced,
// 8 KB, L1-resident) with the same double-buffer prefetch as z_j -- the old
// sampsh LDS staging is dropped. Inner loop identical to the 84.5 us version:
// gram-trick dot form, 160 VALU/chunk.
__global__ __launch_bounds__(TPB, 2) void softnp_main(
    const float* __restrict__ z,
    const int*   __restrict__ pre_knn,
    const int*   __restrict__ samp,
    float*       __restrict__ wsloss,  // [NBLK] per-block loss partial
    float*       __restrict__ wscnt)   // [NBLK] per-block valid count
{
    __shared__ unsigned bits4[NW][ROWS];   // 4 KB, word-interleaved by row
    __shared__ float    zish[ROWS * Ddim]; // 512 B
    __shared__ int      rowsi[ROWS];
    __shared__ float    rden[4][ROWS], rnum[4][ROWS];

    const int t  = threadIdx.x;
    const int i0 = blockIdx.x * ROWS;

    // ---- stage: zero bitsets, z_i -> LDS ----
    #pragma unroll
    for (int c = 0; c < (NW * ROWS) / TPB; ++c)
        ((unsigned*)bits4)[t + c * TPB] = 0u;
    if (t < ROWS * Ddim) zish[t] = z[(size_t)i0 * Ddim + t];
    if (t < ROWS) rowsi[t] = samp[i0 + t];
    __syncthreads();

    // ---- fill bitsets: 4 rows x 30 entries ----
    if (t < ROWS * 32) {
        const int r = t >> 5, k = t & 31;
        if (k < Kk) {
            const int id = pre_knn[(size_t)rowsi[r] * Kk + k];
            atomicOr(&bits4[id >> 5][r], 1u << (id & 31));
        }
    }

    // ---- z_i rows into registers (broadcast LDS reads), |z_i|^2 ----
    float4 zi[ROWS][Ddim / 4];
    const float4* z4s = (const float4*)zish;
    #pragma unroll
    for (int r = 0; r < ROWS; ++r)
        #pragma unroll
        for (int d = 0; d < Ddim / 4; ++d)
            zi[r][d] = z4s[r * (Ddim / 4) + d];

    float si2[ROWS];
    #pragma unroll
    for (int r = 0; r < ROWS; ++r) {
        float s = 0.f;
        #pragma unroll
        for (int d = 0; d < Ddim / 4; ++d)
            s += zi[r][d].x * zi[r][d].x + zi[r][d].y * zi[r][d].y
               + zi[r][d].z * zi[r][d].z + zi[r][d].w * zi[r][d].w;
        si2[r] = s;
    }
    __syncthreads();   // bitset fill complete before main loop reads it

    float den[ROWS] = {0.f, 0.f, 0.f, 0.f};
    float num[ROWS] = {0.f, 0.f, 0.f, 0.f};

    // ---- single-pass j loop over all 2048 j, double-buffered loads ----
    const float4* zg = (const float4*)z;
    int j = t;
    float4 cur[8];
    #pragma unroll
    for (int d = 0; d < 8; ++d) cur[d] = zg[(size_t)j * 8 + d];
    int scur = samp[j];

    #pragma unroll
    for (int c = 0; c < JCH; ++c) {
        float4 nxt[8];
        int snxt = 0;
        if (c + 1 < JCH) {
            #pragma unroll
            for (int d = 0; d < 8; ++d) nxt[d] = zg[(size_t)(j + TPB) * 8 + d];
            snxt = samp[j + TPB];
        }

        float dot[ROWS] = {0.f, 0.f, 0.f, 0.f};
        float sj2 = 0.f;
        #pragma unroll
        for (int d = 0; d < 8; ++d) {
            const float4 v = cur[d];
            sj2 += v.x * v.x + v.y * v.y + v.z * v.z + v.w * v.w;
            #pragma unroll
            for (int r = 0; r < ROWS; ++r)
                dot[r] += zi[r][d].x * v.x + zi[r][d].y * v.y
                        + zi[r][d].z * v.z + zi[r][d].w * v.w;
        }

        const int   sj = scur;
        const uint4 bw = ((const uint4*)bits4)[sj >> 5]; // 4 rows, 1 ds_read_b128
        const unsigned bsel[4] = {bw.x, bw.y, bw.z, bw.w};
        #pragma unroll
        for (int r = 0; r < ROWS; ++r) {
            const float d2 = fmaxf(si2[r] + sj2 - 2.f * dot[r], 0.f);
            const bool diag = (j == i0 + r);
            const float e = diag ? 0.f : __expf(-sqrtf(d2));
            den[r] += e;
            if (!diag && ((bsel[r] >> (sj & 31)) & 1u)) num[r] += e;
        }

        if (c + 1 < JCH) {
            #pragma unroll
            for (int d = 0; d < 8; ++d) cur[d] = nxt[d];
            scur = snxt;
        }
        j += TPB;
    }

    // ---- wave shuffle reduction, 4-wave LDS combine ----
    const int lane = t & 63, wv = t >> 6;
    #pragma unroll
    for (int r = 0; r < ROWS; ++r) {
        #pragma unroll
        for (int off = 32; off > 0; off >>= 1) {
            den[r] += __shfl_xor(den[r], off, 64);
            num[r] += __shfl_xor(num[r], off, 64);
        }
    }
    if (lane == 0) {
        #pragma unroll
        for (int r = 0; r < ROWS; ++r) { rden[wv][r] = den[r]; rnum[wv][r] = num[r]; }
    }
    __syncthreads();

    // ---- per-row loss here (den/num are complete), one pair per block ----
    if (t < ROWS) {
        float D = 0.f, Nm = 0.f;
        #pragma unroll
        for (int w = 0; w < 4; ++w) { D += rden[w][t]; Nm += rnum[w][t]; }
        float lr = 0.f, vr = 0.f;
        if (Nm > 0.f) {            // valid <=> any masked neighbor (no underflow:
            lr = -__logf(Nm / D + 1e-8f);  // exp(-d) >= e^-16 for this data)
            vr = 1.f;
        }
        // lanes 0..3 all active; xor 1,2 stays within the active set
        lr += __shfl_xor(lr, 1, 64); vr += __shfl_xor(vr, 1, 64);
        lr += __shfl_xor(lr, 2, 64); vr += __shfl_xor(vr, 2, 64);
        if (t == 0) { wsloss[blockIdx.x] = lr; wscnt[blockIdx.x] = vr; }
    }
}

// Tiny tail: add-reduce 512 (loss, count) pairs -> out. 4 KB read, no logs.
__global__ __launch_bounds__(TPB) void softnp_final(
    const float* __restrict__ wsloss,
    const float* __restrict__ wscnt,
    float*       __restrict__ out)
{
    __shared__ float rl[4], rc[4];
    const int t = threadIdx.x;
    float L = wsloss[t] + wsloss[t + TPB];
    float C = wscnt[t] + wscnt[t + TPB];
    #pragma unroll
    for (int off = 32; off > 0; off >>= 1) {
        L += __shfl_xor(L, off, 64);
        C += __shfl_xor(C, off, 64);
    }
    const int lane = t & 63, wv = t >> 6;
    if (lane == 0) { rl[wv] = L; rc[wv] = C; }
    __syncthreads();
    if (t == 0) {
        const float Ls = rl[0] + rl[1] + rl[2] + rl[3];
        const float Cs = rc[0] + rc[1] + rc[2] + rc[3];
        out[0] = (Cs > 0.f) ? Ls / Cs : 0.f;
    }
}

extern "C" void kernel_launch(void* const* d_in, const int* in_sizes, int n_in,
                              void* d_out, int out_size, void* d_ws, size_t ws_size,
                              hipStream_t stream)
{
    const float* z       = (const float*)d_in[0];
    const int*   pre_knn = (const int*)d_in[1];
    const int*   samp    = (const int*)d_in[2];
    float*       out     = (float*)d_out;
    float*       wsloss  = (float*)d_ws;           // [NBLK]
    float*       wscnt   = wsloss + NBLK;          // [NBLK]

    // No memset: every ws slot used is overwritten by softnp_main each launch.
    softnp_main<<<dim3(NBLK), dim3(TPB), 0, stream>>>(z, pre_knn, samp, wsloss, wscnt);
    softnp_final<<<dim3(1), dim3(TPB), 0, stream>>>(wsloss, wscnt, out);
}